// Round 4
// baseline (478.820 us; speedup 1.0000x reference)
//
#include <hip/hip_runtime.h>

#define B_    4
#define N_OBJ 24
#define C_    256
#define H_    100
#define W_    100
#define HW_   (H_ * W_)
#define OUT_  7
#define P_    276              // N*(N-1)/2
#define M_    (N_OBJ + P_)     // 300 rois per batch
#define SCALE_ 0.25f
#define CHW_OUT (C_ * OUT_ * OUT_)   // 12544 floats per roi-slot chunk
#define GRID_ 768              // 3 blocks/CU * 256 CUs, LDS-limited co-residency
#define NTHR_ 256

#define PX_TILES   ((HW_ + 63) / 64)          // 157
#define T_TILES    (B_ * (C_ / 64) * PX_TILES) // 2512 transpose tiles
#define CP_JOBS    (B_ * P_ * 2)               // 2208 assemble copies

__device__ __forceinline__ void pair_from_p(int p, int& i, int& j) {
    int ii = 0, rem = p;
    while (rem >= N_OBJ - 1 - ii) { rem -= (N_OBJ - 1 - ii); ++ii; }
    i = ii; j = ii + 1 + rem;
}

// Grid barrier: all GRID_ blocks are co-resident by construction (LDS caps
// occupancy at exactly 3/CU, launch_bounds pins VGPR below the 3-block line).
// bar[0] = arrive count, bar[1] = generation. __threadfence() (agent scope)
// makes phase-N writes visible to phase-N+1 reads across XCDs.
__device__ __forceinline__ void grid_barrier(unsigned* bar) {
    __syncthreads();
    if (threadIdx.x == 0) {
        __threadfence();   // release: drain this block's phase-N writes
        unsigned g = __hip_atomic_load(bar + 1, __ATOMIC_RELAXED, __HIP_MEMORY_SCOPE_AGENT);
        unsigned arrived = __hip_atomic_fetch_add(bar, 1u, __ATOMIC_RELAXED, __HIP_MEMORY_SCOPE_AGENT);
        if (arrived == GRID_ - 1) {
            __hip_atomic_store(bar, 0u, __ATOMIC_RELAXED, __HIP_MEMORY_SCOPE_AGENT);
            __hip_atomic_fetch_add(bar + 1, 1u, __ATOMIC_RELEASE, __HIP_MEMORY_SCOPE_AGENT);
        } else {
            while (__hip_atomic_load(bar + 1, __ATOMIC_RELAXED, __HIP_MEMORY_SCOPE_AGENT) == g)
                __builtin_amdgcn_s_sleep(2);
        }
        __threadfence();   // acquire: invalidate stale L1/L2 before phase N+1 reads
    }
    __syncthreads();
}

__global__ __launch_bounds__(NTHR_, 3) void fused_kernel(
        const float* __restrict__ feat,    // [B, C, H, W]
        const float* __restrict__ boxes,   // [B, N, 4]
        float* __restrict__ out,           // [B*P, 3, C, 49]
        float* __restrict__ featT,         // ws: [B, HW, C]
        float* __restrict__ ws_obj,        // ws: [B, N, C, 49]
        unsigned* __restrict__ bar) {
    __shared__ float lds[CHW_OUT];         // 49 KiB; phase 1 aliases a 64x65 tile on it
    const int t = threadIdx.x;

    // ---------------- phase 1: transpose feat [B,C,H,W] -> featT [B,HW,C]
    {
        float (*tile)[65] = (float (*)[65])lds;
        for (int tl = blockIdx.x; tl < T_TILES; tl += GRID_) {
            const int b    = tl / ((C_ / 64) * PX_TILES);
            const int rem  = tl - b * ((C_ / 64) * PX_TILES);
            const int c0   = (rem / PX_TILES) * 64;
            const int px0  = (rem - (rem / PX_TILES) * PX_TILES) * 64;
            const int cl   = t >> 6;    // 0..3
            const int px   = t & 63;
            __syncthreads();            // protect lds reuse across iterations
#pragma unroll
            for (int k = 0; k < 16; ++k) {
                const int c_loc = cl + k * 4;
                const int gpx   = px0 + px;
                tile[c_loc][px] = (gpx < HW_)
                    ? feat[((size_t)b * C_ + c0 + c_loc) * HW_ + gpx] : 0.0f;
            }
            __syncthreads();
            const int c2 = t & 63;
            const int pl = t >> 6;
#pragma unroll
            for (int k = 0; k < 16; ++k) {
                const int px_l = pl + k * 4;
                const int gpx  = px0 + px_l;
                if (gpx < HW_)
                    featT[((size_t)b * HW_ + gpx) * C_ + c0 + c2] = tile[c2][px_l];
            }
        }
    }
    grid_barrier(bar);

    // ---------------- phase 2: roi-align. One block per roi (grid-stride).
    // Lane covers 4 channels (float4), wave covers a bin; LDS [c][s] tile
    // converts channel-last compute into channel-major contiguous stores.
    {
        const int lane = t & 63;
        const int wv   = t >> 6;   // 0..3
        for (int r = blockIdx.x; r < B_ * M_; r += GRID_) {
            const int b = r / M_;
            const int m = r - b * M_;

            float x1, y1, x2, y2;
            if (m < N_OBJ) {
                const float* bp = boxes + ((size_t)b * N_OBJ + m) * 4;
                x1 = bp[0]; y1 = bp[1]; x2 = bp[2]; y2 = bp[3];
            } else {
                int i, j; pair_from_p(m - N_OBJ, i, j);
                const float* b1 = boxes + ((size_t)b * N_OBJ + i) * 4;
                const float* b2 = boxes + ((size_t)b * N_OBJ + j) * 4;
                x1 = fminf(b1[0], b2[0]); y1 = fminf(b1[1], b2[1]);
                x2 = fmaxf(b1[2], b2[2]); y2 = fmaxf(b1[3], b2[3]);
            }
            x1 *= SCALE_; y1 *= SCALE_; x2 *= SCALE_; y2 *= SCALE_;
            const float bin_w = fmaxf(x2 - x1, 1.0f) * (1.0f / OUT_);
            const float bin_h = fmaxf(y2 - y1, 1.0f) * (1.0f / OUT_);

            const float4* fbase = (const float4*)(featT + (size_t)b * HW_ * C_) + lane;
            __syncthreads();            // lds reuse across roi iterations
            for (int s = wv; s < OUT_ * OUT_; s += 4) {
                const int ph = s / OUT_, pw = s - ph * OUT_;
                float4 acc = make_float4(0.f, 0.f, 0.f, 0.f);
#pragma unroll
                for (int iy = 0; iy < 2; ++iy) {
                    const float Y  = y1 + ((float)ph + (iy ? 0.75f : 0.25f)) * bin_h;
                    const bool vy  = (Y > -1.0f) && (Y < (float)H_);
                    const float Yc = fminf(fmaxf(Y, 0.0f), (float)(H_ - 1));
                    const int  y0  = (int)floorf(Yc);
                    const float ly = Yc - (float)y0;
                    const float hy = 1.0f - ly;
                    const int  y1i = min(y0 + 1, H_ - 1);
#pragma unroll
                    for (int ix = 0; ix < 2; ++ix) {
                        const float X  = x1 + ((float)pw + (ix ? 0.75f : 0.25f)) * bin_w;
                        const bool vx  = (X > -1.0f) && (X < (float)W_);
                        const float Xc = fminf(fmaxf(X, 0.0f), (float)(W_ - 1));
                        const int  x0  = (int)floorf(Xc);
                        const float lx = Xc - (float)x0;
                        const float hx = 1.0f - lx;
                        const int  x1i = min(x0 + 1, W_ - 1);
                        const float vs = (vy && vx) ? 0.25f : 0.0f;  // mean of 4 samples
                        const float w00 = vs * hy * hx, w01 = vs * hy * lx;
                        const float w10 = vs * ly * hx, w11 = vs * ly * lx;
                        const float4 f00 = fbase[(y0  * W_ + x0 ) * (C_ / 4)];
                        const float4 f01 = fbase[(y0  * W_ + x1i) * (C_ / 4)];
                        const float4 f10 = fbase[(y1i * W_ + x0 ) * (C_ / 4)];
                        const float4 f11 = fbase[(y1i * W_ + x1i) * (C_ / 4)];
                        acc.x += w00 * f00.x + w01 * f01.x + w10 * f10.x + w11 * f11.x;
                        acc.y += w00 * f00.y + w01 * f01.y + w10 * f10.y + w11 * f11.y;
                        acc.z += w00 * f00.z + w01 * f01.z + w10 * f10.z + w11 * f11.z;
                        acc.w += w00 * f00.w + w01 * f01.w + w10 * f10.w + w11 * f11.w;
                    }
                }
                const int c0 = lane * 4;   // [c][s]; 8-way bank conflict but only 196 ds_writes/roi
                lds[(c0 + 0) * 49 + s] = acc.x;
                lds[(c0 + 1) * 49 + s] = acc.y;
                lds[(c0 + 2) * 49 + s] = acc.z;
                lds[(c0 + 3) * 49 + s] = acc.w;
            }
            __syncthreads();

            float* dst = (m < N_OBJ)
                ? (ws_obj + ((size_t)b * N_OBJ + m) * CHW_OUT)
                : (out + (((size_t)(b * P_ + (m - N_OBJ))) * 3 + 2) * CHW_OUT);
            const float4* s4 = (const float4*)lds;
            float4* d4 = (float4*)dst;
            for (int idx = t; idx < CHW_OUT / 4; idx += NTHR_)
                d4[idx] = s4[idx];
        }
    }
    grid_barrier(bar);

    // ---------------- phase 3: fan object tiles to pair slots 0/1
    for (int job = blockIdx.x; job < CP_JOBS; job += GRID_) {
        const int slot = job & 1;
        const int bp   = job >> 1;
        const int b = bp / P_;
        const int p = bp - b * P_;
        int i, j; pair_from_p(p, i, j);
        const int n = slot ? j : i;
        const float4* src = (const float4*)(ws_obj + ((size_t)b * N_OBJ + n) * CHW_OUT);
        float4* dst = (float4*)(out + (((size_t)bp) * 3 + slot) * CHW_OUT);
        for (int idx = t; idx < CHW_OUT / 4; idx += NTHR_)
            dst[idx] = src[idx];
    }
}

extern "C" void kernel_launch(void* const* d_in, const int* in_sizes, int n_in,
                              void* d_out, int out_size, void* d_ws, size_t ws_size,
                              hipStream_t stream) {
    const float* feat  = (const float*)d_in[0];   // [B,C,H,W] fp32
    const float* boxes = (const float*)d_in[1];   // [B,N,4]  fp32
    float* out = (float*)d_out;                   // [B*P,3,C,7,7] fp32

    float* featT  = (float*)d_ws;                           // 40.96 MB
    float* ws_obj = featT + (size_t)B_ * HW_ * C_;          // 4.82 MB
    unsigned* bar = (unsigned*)(ws_obj + (size_t)B_ * N_OBJ * CHW_OUT);

    (void)hipMemsetAsync(bar, 0, 2 * sizeof(unsigned), stream);   // ws is re-poisoned 0xAA
    fused_kernel<<<GRID_, NTHR_, 0, stream>>>(feat, boxes, out, featT, ws_obj, bar);
}

// Round 5
// 252.140 us; speedup vs baseline: 1.8990x; 1.8990x over previous
//
#include <hip/hip_runtime.h>

#define B_    4
#define N_OBJ 24
#define C_    256
#define H_    100
#define W_    100
#define HW_   (H_ * W_)
#define OUT_  7
#define P_    276              // N*(N-1)/2
#define M_    (N_OBJ + P_)     // 300 rois per batch
#define SCALE_ 0.25f
#define CHW_OUT (C_ * OUT_ * OUT_)   // 12544 floats per roi-slot chunk

typedef float f4_t __attribute__((ext_vector_type(4)));

__device__ __forceinline__ void pair_from_p(int p, int& i, int& j) {
    int ii = 0, rem = p;
    while (rem >= N_OBJ - 1 - ii) { rem -= (N_OBJ - 1 - ii); ++ii; }
    i = ii; j = ii + 1 + rem;
}

// ---------------------------------------------------------------- transpose
// feat [B,C,H,W] -> featT [B,H*W,C]
__global__ __launch_bounds__(256) void transpose_kernel(
        const float* __restrict__ feat, float* __restrict__ featT) {
    __shared__ float tile[64][65];
    const int b   = blockIdx.z;
    const int c0  = blockIdx.y * 64;
    const int px0 = blockIdx.x * 64;
    const int t   = threadIdx.x;
    const int cl  = t >> 6;   // 0..3
    const int px  = t & 63;
#pragma unroll
    for (int k = 0; k < 16; ++k) {
        const int c_loc = cl + k * 4;
        const int gpx   = px0 + px;
        tile[c_loc][px] = (gpx < HW_)
            ? feat[((size_t)b * C_ + c0 + c_loc) * HW_ + gpx] : 0.0f;
    }
    __syncthreads();
    const int c2 = t & 63;
    const int pl = t >> 6;
#pragma unroll
    for (int k = 0; k < 16; ++k) {
        const int px_l = pl + k * 4;
        const int gpx  = px0 + px_l;
        if (gpx < HW_)
            featT[((size_t)b * HW_ + gpx) * C_ + c0 + c2] = tile[c2][px_l];
    }
}

// ---------------------------------------------------------------- roi align
// One block per roi. Lane covers 4 channels (float4), wave covers a bin.
// Key fix vs R1/R2: per bin, compute ALL 16 corner offsets+weights first,
// then issue 16 independent float4 loads as a batch, THEN accumulate —
// ~16 loads in flight per wave instead of ~1 (the acc-chain serialization
// that made R1's roi kernel latency-bound at ~8.5 TB/s effective).
// Block swizzle: rois of batch b go to XCDs {2b,2b+1} (blockIdx%8 round-
// robin heuristic) so featT's 10.2 MB/batch stays mostly L2-resident.
__global__ __launch_bounds__(256) void roi_kernel(
        const float* __restrict__ featT,   // [B, HW, C]
        const float* __restrict__ boxes,   // [B, N, 4]
        float* __restrict__ out,           // [B*P, 3, C, 49]
        float* __restrict__ ws_obj) {      // [B, N, C, 49]
    __shared__ float lds[CHW_OUT];         // 49 KiB -> 3 blocks/CU
    const int xcd = blockIdx.x & 7;
    const int b   = xcd >> 1;                               // batch 0..3
    const int m   = ((blockIdx.x >> 3) << 1) | (xcd & 1);   // roi 0..299

    float x1, y1, x2, y2;
    if (m < N_OBJ) {
        const float* bp = boxes + ((size_t)b * N_OBJ + m) * 4;
        x1 = bp[0]; y1 = bp[1]; x2 = bp[2]; y2 = bp[3];
    } else {
        int i, j; pair_from_p(m - N_OBJ, i, j);
        const float* b1 = boxes + ((size_t)b * N_OBJ + i) * 4;
        const float* b2 = boxes + ((size_t)b * N_OBJ + j) * 4;
        x1 = fminf(b1[0], b2[0]); y1 = fminf(b1[1], b2[1]);
        x2 = fmaxf(b1[2], b2[2]); y2 = fmaxf(b1[3], b2[3]);
    }
    x1 *= SCALE_; y1 *= SCALE_; x2 *= SCALE_; y2 *= SCALE_;
    const float bin_w = fmaxf(x2 - x1, 1.0f) * (1.0f / OUT_);
    const float bin_h = fmaxf(y2 - y1, 1.0f) * (1.0f / OUT_);

    const int lane = threadIdx.x & 63;
    const int wv   = threadIdx.x >> 6;   // 0..3
    const f4_t* fbase = (const f4_t*)(featT + (size_t)b * HW_ * C_) + lane;

    for (int s = wv; s < OUT_ * OUT_; s += 4) {
        const int ph = s / OUT_, pw = s - ph * OUT_;

        float ywt[2][2]; int yi[2][2];
#pragma unroll
        for (int iy = 0; iy < 2; ++iy) {
            const float Y  = y1 + ((float)ph + (iy ? 0.75f : 0.25f)) * bin_h;
            const float vy = (Y > -1.0f && Y < (float)H_) ? 1.0f : 0.0f;
            const float Yc = fminf(fmaxf(Y, 0.0f), (float)(H_ - 1));
            const int  y0  = (int)floorf(Yc);
            const float ly = Yc - (float)y0;
            yi[iy][0] = y0; yi[iy][1] = min(y0 + 1, H_ - 1);
            ywt[iy][0] = vy * (1.0f - ly); ywt[iy][1] = vy * ly;
        }
        float xwt[2][2]; int xi[2][2];
#pragma unroll
        for (int ix = 0; ix < 2; ++ix) {
            const float X  = x1 + ((float)pw + (ix ? 0.75f : 0.25f)) * bin_w;
            const float vx = (X > -1.0f && X < (float)W_) ? 0.25f : 0.0f; // folds mean/4
            const float Xc = fminf(fmaxf(X, 0.0f), (float)(W_ - 1));
            const int  x0  = (int)floorf(Xc);
            const float lx = Xc - (float)x0;
            xi[ix][0] = x0; xi[ix][1] = min(x0 + 1, W_ - 1);
            xwt[ix][0] = vx * (1.0f - lx); xwt[ix][1] = vx * lx;
        }

        int   offs[16]; float wts[16];
#pragma unroll
        for (int k = 0; k < 16; ++k) {
            const int iy = k >> 3, ix = (k >> 2) & 1, cy = (k >> 1) & 1, cx = k & 1;
            offs[k] = (yi[iy][cy] * W_ + xi[ix][cx]) * (C_ / 4);
            wts[k]  = ywt[iy][cy] * xwt[ix][cx];
        }
        f4_t f[16];
#pragma unroll
        for (int k = 0; k < 16; ++k) f[k] = fbase[offs[k]];   // 16 loads in flight
        f4_t acc = (f4_t){0.f, 0.f, 0.f, 0.f};
#pragma unroll
        for (int k = 0; k < 16; ++k) acc += wts[k] * f[k];

        const int c0 = lane * 4;   // [c][s] tile: stride 49 -> conflict-free (gcd(17,32)=1)
        lds[(c0 + 0) * 49 + s] = acc.x;
        lds[(c0 + 1) * 49 + s] = acc.y;
        lds[(c0 + 2) * 49 + s] = acc.z;
        lds[(c0 + 3) * 49 + s] = acc.w;
    }
    __syncthreads();

    const f4_t* s4 = (const f4_t*)lds;
    if (m < N_OBJ) {
        f4_t* d4 = (f4_t*)(ws_obj + ((size_t)b * N_OBJ + m) * CHW_OUT);
        for (int idx = threadIdx.x; idx < CHW_OUT / 4; idx += 256)
            d4[idx] = s4[idx];
    } else {
        f4_t* d4 = (f4_t*)(out + (((size_t)(b * P_ + (m - N_OBJ))) * 3 + 2) * CHW_OUT);
        for (int idx = threadIdx.x; idx < CHW_OUT / 4; idx += 256)
            __builtin_nontemporal_store(s4[idx], d4 + idx);   // don't evict featT from L2
    }
}

// ---------------------------------------------------------------- assemble
// Fan object pooled tiles out to pair slots 0 (i) and 1 (j).
__global__ __launch_bounds__(256) void assemble_kernel(
        const float* __restrict__ ws_obj, float* __restrict__ out) {
    const int bp   = blockIdx.x;          // 0 .. B*P-1
    const int slot = blockIdx.y;          // 0 or 1
    const int b = bp / P_;
    const int p = bp - b * P_;
    int i, j; pair_from_p(p, i, j);
    const int n = slot ? j : i;
    const f4_t* src = (const f4_t*)(ws_obj + ((size_t)b * N_OBJ + n) * CHW_OUT);
    f4_t* dst = (f4_t*)(out + (((size_t)bp) * 3 + slot) * CHW_OUT);
    for (int idx = threadIdx.x; idx < CHW_OUT / 4; idx += 256)
        __builtin_nontemporal_store(src[idx], dst + idx);
}

extern "C" void kernel_launch(void* const* d_in, const int* in_sizes, int n_in,
                              void* d_out, int out_size, void* d_ws, size_t ws_size,
                              hipStream_t stream) {
    const float* feat  = (const float*)d_in[0];   // [B,C,H,W] fp32
    const float* boxes = (const float*)d_in[1];   // [B,N,4]  fp32
    float* out = (float*)d_out;                   // [B*P,3,C,7,7] fp32

    float* featT  = (float*)d_ws;                          // 40.96 MB
    float* ws_obj = featT + (size_t)B_ * HW_ * C_;         // 4.82 MB

    transpose_kernel<<<dim3((HW_ + 63) / 64, C_ / 64, B_), 256, 0, stream>>>(feat, featT);
    roi_kernel<<<B_ * M_, 256, 0, stream>>>(featT, boxes, out, ws_obj);
    assemble_kernel<<<dim3(B_ * P_, 2), 256, 0, stream>>>(ws_obj, out);
}